// Round 10
// baseline (446.863 us; speedup 1.0000x reference)
//
#include <hip/hip_runtime.h>
#include <hip/hip_bf16.h>

#define B_  2
#define T_  2048
#define H_  2048
#define NH_ 16
#define HD_ 128
#define QKVN 6144

typedef __attribute__((ext_vector_type(8))) short  short8;   // 8 bf16 in 4 VGPRs
typedef __attribute__((ext_vector_type(4))) float  floatx4;  // MFMA C/D

__device__ __forceinline__ unsigned short f2bf(float x) {
    union { float f; unsigned int u; } c; c.f = x;
    unsigned int r = c.u + 0x7FFF + ((c.u >> 16) & 1);   // RNE
    return (unsigned short)(r >> 16);
}
__device__ __forceinline__ float bf2f(unsigned short u) {
    union { float f; unsigned int i; } c;
    c.i = ((unsigned int)u) << 16;
    return c.f;
}

// async global->LDS, 16B per lane; LDS dest is wave-uniform base + lane*16
__device__ __forceinline__ void gload_lds16(const void* g, void* l) {
    __builtin_amdgcn_global_load_lds(
        (__attribute__((address_space(1))) void*)g,
        (__attribute__((address_space(3))) void*)l, 16, 0, 0);
}

// ---------------- fp32 -> bf16 convert (vector4) ---------------------------------
__global__ __launch_bounds__(256) void f32_to_bf16(
    const float* __restrict__ src, unsigned short* __restrict__ dst, int n)
{
    const int i = (blockIdx.x * 256 + threadIdx.x) * 4;
    if (i < n) {
        float4 v = *(const float4*)(src + i);
        ushort4 o;
        o.x = f2bf(v.x); o.y = f2bf(v.y); o.z = f2bf(v.z); o.w = f2bf(v.w);
        *(ushort4*)(dst + i) = o;
    }
}

#define BAR()   asm volatile("s_barrier" ::: "memory")

// ---------------- templated fragment helpers (all indices compile-time) ----------
template<int MI, int BASE>
__device__ __forceinline__ void ldAf(short8 (&d)[MI/2][2], const unsigned short* src,
                                     int wm, int n16, int quad)
{
    #pragma unroll
    for (int mi = 0; mi < MI/2; ++mi)
        #pragma unroll
        for (int ks = 0; ks < 2; ++ks)
            d[mi][ks] = *(const short8*)(src + (wm*(MI*16) + (BASE+mi)*16 + n16) * 64
                                             + (((ks*4 + quad) ^ (n16 & 7)) * 8));
}
template<int NI, int BASE>
__device__ __forceinline__ void ldBf(short8 (&d)[NI/2][2], const unsigned short* src,
                                     int wn, int n16, int quad)
{
    #pragma unroll
    for (int ni = 0; ni < NI/2; ++ni)
        #pragma unroll
        for (int ks = 0; ks < 2; ++ks)
            d[ni][ks] = *(const short8*)(src + (wn*(NI*16) + (BASE+ni)*16 + n16) * 64
                                             + (((ks*4 + quad) ^ (n16 & 7)) * 8));
}
// one C-quadrant x K=64
template<int MI, int NI, int MB, int NB>
__device__ __forceinline__ void mq(floatx4 (&acc)[MI][NI],
                                   const short8 (&a)[MI/2][2],
                                   const short8 (&b)[NI/2][2])
{
    #pragma unroll
    for (int ks = 0; ks < 2; ++ks)
        #pragma unroll
        for (int mi = 0; mi < MI/2; ++mi)
            #pragma unroll
            for (int ni = 0; ni < NI/2; ++ni)
                acc[MB+mi][NB+ni] = __builtin_amdgcn_mfma_f32_16x16x32_bf16(
                    a[mi][ks], b[ni][ks], acc[MB+mi][NB+ni], 0, 0, 0);
}

// ---------------- one K-tile: free-running body, ONE barrier ---------------------
// Round-5/9's 8-barrier phase lockstep measured fully serial (4762 cyc/tile =
// 620 MFMA + 2304 LDS + ~1840 barrier overhead). Minimal correct sync is ONE
// barrier per tile: it publishes buf[t+1] (after counted vmcnt) and separates
// reads-of-buf[t-1] from tile-(t+1)'s staging into that buffer. Body is plain
// C++: compiler emits fine-grained lgkmcnt for ds_read->MFMA (m97 finding) and
// waves drift so LDS reads overlap other waves' MFMAs.
// Triple-buffer enables counted vmcnt(6): staging for t+2 stays in flight
// across the publish of t+1 (m218 counted-vs-drain, +38-73% there).
template<int MI, int NI>
__device__ __forceinline__ void gt_tile(
    const unsigned short* Ac, const unsigned short* Bc,
    unsigned short* An2, unsigned short* Bn2,   // buf (t+2)%3
    const unsigned short* Ap, const unsigned short* Bp,
    size_t knext, bool pre, int tid, int K,
    int wm, int wn, int n16, int quad,
    floatx4 (&acc)[MI][NI])
{
    constexpr int MH = MI/2, NH = NI/2;
    constexpr int AG = (MI*32)/64;   // A gloads per tile per thread
    constexpr int BG = (NI*64)/64;   // B gloads per tile per thread

    if (pre) {
        #pragma unroll
        for (int h = 0; h < AG; ++h)
            gload_lds16(Ap + knext + (size_t)h * 64 * K, An2 + h * 4096 + (size_t)tid * 8);
        #pragma unroll
        for (int h = 0; h < BG; ++h)
            gload_lds16(Bp + knext + (size_t)h * 64 * K, Bn2 + h * 4096 + (size_t)tid * 8);
    }

    short8 aL[MH][2], aH[MH][2], bL[NH][2], bH[NH][2];
    ldAf<MI, 0 >(aL, Ac, wm, n16, quad);
    ldBf<NI, 0 >(bL, Bc, wn, n16, quad);
    ldAf<MI, MH>(aH, Ac, wm, n16, quad);
    ldBf<NI, NH>(bH, Bc, wn, n16, quad);

    mq<MI, NI, 0,  0 >(acc, aL, bL);
    mq<MI, NI, 0,  NH>(acc, aL, bH);
    mq<MI, NI, MH, 0 >(acc, aH, bL);
    mq<MI, NI, MH, NH>(acc, aH, bH);

    // publish buf[t+1]; keep t+2's 6 loads in flight (counted, never drain-0
    // in steady state). lgkm is already drained per-wave by the last MFMA's
    // operand wait (in-order DS), so reads of buf[t-1] are complete here.
    if (pre) asm volatile("s_waitcnt vmcnt(6)" ::: "memory");
    else     asm volatile("s_waitcnt vmcnt(0)" ::: "memory");
    BAR();
}

// ---------------- tiled bf16 GEMM: Y[M,N] = A[M,K] @ W[N,K]^T --------------------
// 8 waves (2M x 4N), BM=128 BN=256 BK=64, TRIPLE-buffered 144KB LDS,
// granule-XOR swizzle both-sides, 1 barrier/K-tile, vmcnt(6).
// QKV: grid 24x32 = 768 blocks = 3.0 exact rounds; Wo: 8x32 = 256 = 1.0 round.
template<int MI, int NI, bool BF16_OUT>
__global__ __launch_bounds__(512, 1) void gemm_t(
    const unsigned short* __restrict__ A,   // [M,K] bf16
    const unsigned short* __restrict__ W,   // [N,K] bf16
    float* __restrict__ Yf, unsigned short* __restrict__ Yb,
    int M, int N, int K)
{
    constexpr int BM = MI*32, BN = NI*64;
    constexpr int AG = BM/64, BG = BN/64;
    __shared__ __attribute__((aligned(16))) unsigned short As[3][BM * 64];
    __shared__ __attribute__((aligned(16))) unsigned short Bs[3][BN * 64];

    const int tid  = threadIdx.x;
    const int lane = tid & 63;
    const int n16  = lane & 15;
    const int quad = lane >> 4;
    const int w    = tid >> 6;      // 0..7
    const int wm   = w >> 2;        // 0..1  (M panel)
    const int wn   = w & 3;         // 0..3  (N panel)

    const int m0 = blockIdx.y * BM;
    const int n0 = blockIdx.x * BN;

    // staging: slot s -> LDS row r = s>>3 (64 rows per gload group), granule s&7.
    // source granule = (s&7) ^ (r&7); (r+64)&7 == r&7 so one base serves all h.
    const int r0  = tid >> 3;
    const int g0  = ((tid & 7) ^ (r0 & 7)) * 8;
    const unsigned short* Ap = A + (size_t)(m0 + r0) * K + g0;
    const unsigned short* Bp = W + (size_t)(n0 + r0) * K + g0;

    floatx4 acc[MI][NI];
    #pragma unroll
    for (int i = 0; i < MI; i++)
        #pragma unroll
        for (int j = 0; j < NI; j++) acc[i][j] = (floatx4){0.f, 0.f, 0.f, 0.f};

    const int nt = K >> 6;          // 32 for K=2048

    // prologue: stage tile 0 -> buf0, tile 1 -> buf1 (6 gloads each);
    // vmcnt(6) drains tile-0's (in-order), leaves tile-1's in flight.
    #pragma unroll
    for (int h = 0; h < AG; ++h)
        gload_lds16(Ap + (size_t)h * 64 * K, &As[0][h * 4096 + (size_t)tid * 8]);
    #pragma unroll
    for (int h = 0; h < BG; ++h)
        gload_lds16(Bp + (size_t)h * 64 * K, &Bs[0][h * 4096 + (size_t)tid * 8]);
    #pragma unroll
    for (int h = 0; h < AG; ++h)
        gload_lds16(Ap + 64 + (size_t)h * 64 * K, &As[1][h * 4096 + (size_t)tid * 8]);
    #pragma unroll
    for (int h = 0; h < BG; ++h)
        gload_lds16(Bp + 64 + (size_t)h * 64 * K, &Bs[1][h * 4096 + (size_t)tid * 8]);
    asm volatile("s_waitcnt vmcnt(6)" ::: "memory");
    BAR();

    const unsigned short *a0 = &As[0][0], *a1 = &As[1][0], *a2 = &As[2][0];
    const unsigned short *b0 = &Bs[0][0], *b1 = &Bs[1][0], *b2 = &Bs[2][0];

    for (int t = 0; t < nt; ++t) {
        gt_tile<MI, NI>(a0, b0, (unsigned short*)a2, (unsigned short*)b2,
                        Ap, Bp, (size_t)(t + 2) << 6, (t + 2) < nt,
                        tid, K, wm, wn, n16, quad, acc);
        const unsigned short* ta = a0; a0 = a1; a1 = a2; a2 = ta;
        const unsigned short* tb = b0; b0 = b1; b1 = b2; b2 = tb;
    }

    // C/D: col = lane&15, row = quad*4 + reg  (verified m89/m91)
    #pragma unroll
    for (int mi = 0; mi < MI; ++mi) {
        const size_t rb = (size_t)(m0 + wm*(MI*16) + mi*16 + quad*4);
        #pragma unroll
        for (int r = 0; r < 4; ++r) {
            const size_t row = rb + r;
            #pragma unroll
            for (int ni = 0; ni < NI; ++ni) {
                const size_t col = n0 + wn*(NI*16) + ni*16 + n16;
                if (BF16_OUT) Yb[row * N + col] = f2bf(acc[mi][ni][r]);
                else          Yf[row * N + col] = acc[mi][ni][r];
            }
        }
    }
}

// ---------------- RoPE: bf16 qkv[:, 0:4096] -> bf16 [BH][T][HD] (q scaled) -------
__global__ __launch_bounds__(256) void rope_convert_qk(
    const unsigned short* __restrict__ qkvp,   // [B*T, 6144]
    const float* __restrict__ cosp, const float* __restrict__ sinp,
    unsigned short* __restrict__ qh, unsigned short* __restrict__ kh)
{
    const int idx  = blockIdx.x * 256 + threadIdx.x;
    const int d    = idx & 63;
    const int rest = idx >> 6;
    const int h    = rest & 15;
    const int bt   = rest >> 4;
    const int t    = bt & (T_ - 1);
    const int b    = bt >> 11;                       // T_ = 2048
    const size_t ibase = (size_t)bt * QKVN + h * HD_;
    const size_t obase = (((size_t)b * NH_ + h) * T_ + t) * HD_;

    const float c0 = cosp[t*HD_ + d],      s0 = sinp[t*HD_ + d];
    const float c1 = cosp[t*HD_ + d + 64], s1 = sinp[t*HD_ + d + 64];
    const float sc = 0.08838834764831845f;           // 1/sqrt(128)

    float q0 = bf2f(qkvp[ibase + d]), q1 = bf2f(qkvp[ibase + d + 64]);
    qh[obase + d]      = f2bf((q0*c0 - q1*s0) * sc);
    qh[obase + d + 64] = f2bf((q1*c1 + q0*s1) * sc);

    float k0 = bf2f(qkvp[ibase + 2048 + d]), k1 = bf2f(qkvp[ibase + 2048 + d + 64]);
    kh[obase + d]      = f2bf(k0*c0 - k1*s0);
    kh[obase + d + 64] = f2bf(k1*c1 + k0*s1);
}

// ---------------- V transpose: qkv[:, 4096:6144] -> bf16 [BH][HD][T] -------------
__global__ __launch_bounds__(256) void transpose_v(
    const unsigned short* __restrict__ qkvp, unsigned short* __restrict__ vh)
{
    __shared__ float tile[64][65];
    const int t0 = blockIdx.x * 64;
    const int d0 = blockIdx.y * 64;
    const int bh = blockIdx.z;
    const int b  = bh >> 4, h = bh & 15;

    for (int i = threadIdx.x; i < 4096; i += 256) {
        int r = i >> 6, c = i & 63;
        tile[r][c] = bf2f(qkvp[((size_t)b*T_ + t0 + r) * QKVN + 4096 + h*HD_ + d0 + c]);
    }
    __syncthreads();
    for (int i = threadIdx.x; i < 4096; i += 256) {
        int dr = i >> 6, tc = i & 63;
        vh[((size_t)bh * HD_ + d0 + dr) * T_ + t0 + tc] = f2bf(tile[tc][dr]);  // exact round-trip
    }
}

// ---------------- MFMA flash attention (round-0 verified) ------------------------
__global__ __launch_bounds__(256, 4) void attn_mfma(
    const unsigned short* __restrict__ qh,   // [BH][T][HD] (pre-scaled)
    const unsigned short* __restrict__ kh,   // [BH][T][HD]
    const unsigned short* __restrict__ vh,   // [BH][HD][T]
    unsigned short* __restrict__ o)          // [B][T][H] bf16
{
    __shared__ __attribute__((aligned(16))) unsigned short Ks[64 * 128];   // 16 KB
    __shared__ __attribute__((aligned(16))) unsigned short Vs[128 * 64];   // 16 KB
    __shared__ __attribute__((aligned(16))) unsigned short Ps[4][16 * 64]; //  8 KB

    const int tid  = threadIdx.x;
    const int lane = tid & 63;
    const int w    = tid >> 6;
    const int n16  = lane & 15;
    const int quad = lane >> 4;

    // work-balanced bijective remap: per-CU {a,a+8,23-a,31-a} = 66 tiles, shared bh
    const int id   = blockIdx.y * gridDim.x + blockIdx.x;
    const int bh   = id & 31;
    const int a    = (id >> 5) & 7;
    const int u    = id >> 8;
    const int qblk = (u < 2) ? (a + (u << 3)) : ((23 + ((u & 1) << 3)) - a);

    const int q0w  = qblk * 64 + w * 16;

    short8 qf[4];
    {
        const size_t qbase = ((size_t)bh * T_ + q0w + n16) * HD_ + quad * 8;
        #pragma unroll
        for (int c = 0; c < 4; c++)
            qf[c] = *(const short8*)(qh + qbase + c * 32);
    }

    const int rk   = tid >> 4;
    const int gk16 = ((tid & 15) ^ (rk & 7)) * 8;
    const unsigned short* ksrc = kh + (size_t)bh * T_ * HD_ + (size_t)rk * HD_ + gk16;
    const int dv   = tid >> 3;
    const int gv16 = ((tid & 7) ^ (dv & 7)) * 8;
    const unsigned short* vsrc = vh + (size_t)bh * HD_ * T_ + (size_t)dv * T_ + gv16;

    floatx4 of[8];
    #pragma unroll
    for (int i = 0; i < 8; i++) of[i] = (floatx4){0.f, 0.f, 0.f, 0.f};
    float mrow[4], lrow[4];
    #pragma unroll
    for (int r = 0; r < 4; r++) { mrow[r] = -INFINITY; lrow[r] = 0.f; }

    const int nkv = qblk + 1;
    for (int kv = 0; kv < nkv; kv++) {
        const int kv0 = kv * 64;
        __syncthreads();
        #pragma unroll
        for (int it = 0; it < 4; it++)
            gload_lds16(ksrc + (size_t)(kv0 + it * 16) * HD_,
                        Ks + (size_t)(it * 256 + tid) * 8);
        #pragma unroll
        for (int it = 0; it < 4; it++)
            gload_lds16(vsrc + kv0 + (size_t)(it * 32) * T_,
                        Vs + (size_t)(it * 256 + tid) * 8);
        __syncthreads();   // compiler drains vmcnt(0) before s_barrier

        floatx4 s[4];
        #pragma unroll
        for (int kg = 0; kg < 4; kg++) {
            floatx4 acc = {0.f, 0.f, 0.f, 0.f};
            #pragma unroll
            for (int c = 0; c < 4; c++) {
                short8 kf = *(const short8*)(Ks + (kg*16 + n16) * 128
                                                + (((c*4 + quad) ^ (n16 & 7)) * 8));
                acc = __builtin_amdgcn_mfma_f32_16x16x32_bf16(qf[c], kf, acc, 0, 0, 0);
            }
            s[kg] = acc;
        }

        const bool needmask = (kv0 + 63 > q0w);

        float alpha[4];
        #pragma unroll
        for (int r = 0; r < 4; r++) {
            const int qrow = q0w + quad * 4 + r;
            float v0 = s[0][r], v1 = s[1][r], v2 = s[2][r], v3 = s[3][r];
            if (needmask) {
                if (kv0 +  0 + n16 > qrow) v0 = -INFINITY;
                if (kv0 + 16 + n16 > qrow) v1 = -INFINITY;
                if (kv0 + 32 + n16 > qrow) v2 = -INFINITY;
                if (kv0 + 48 + n16 > qrow) v3 = -INFINITY;
            }

            float tm = fmaxf(fmaxf(v0, v1), fmaxf(v2, v3));
            tm = fmaxf(tm, __shfl_xor(tm, 1));
            tm = fmaxf(tm, __shfl_xor(tm, 2));
            tm = fmaxf(tm, __shfl_xor(tm, 4));
            tm = fmaxf(tm, __shfl_xor(tm, 8));

            const float mnew = fmaxf(mrow[r], tm);
            const float aa   = __expf(mrow[r] - mnew);
            const float p0 = __expf(v0 - mnew), p1 = __expf(v1 - mnew);
            const float p2 = __expf(v2 - mnew), p3 = __expf(v3 - mnew);

            float ts = p0 + p1 + p2 + p3;
            ts += __shfl_xor(ts, 1);
            ts += __shfl_xor(ts, 2);
            ts += __shfl_xor(ts, 4);
            ts += __shfl_xor(ts, 8);

            lrow[r] = lrow[r] * aa + ts;
            mrow[r] = mnew;
            alpha[r] = aa;

            const int pr = quad * 4 + r;
            const int sx = pr & 7;
            unsigned short* pp = &Ps[w][pr * 64];
            const int g0p = n16 >> 3, e = n16 & 7;
            pp[((g0p    ) ^ sx) * 8 + e] = f2bf(p0);
            pp[((g0p + 2) ^ sx) * 8 + e] = f2bf(p1);
            pp[((g0p + 4) ^ sx) * 8 + e] = f2bf(p2);
            pp[((g0p + 6) ^ sx) * 8 + e] = f2bf(p3);
        }
        #pragma unroll
        for (int nt = 0; nt < 8; nt++)
            #pragma unroll
            for (int r = 0; r < 4; r++) of[nt][r] *= alpha[r];

        short8 pf0 = *(const short8*)(&Ps[w][n16 * 64 + ((quad       ^ (n16 & 7)) * 8)]);
        short8 pf1 = *(const short8*)(&Ps[w][n16 * 64 + (((quad + 4) ^ (n16 & 7)) * 8)]);
        #pragma unroll
        for (int nt = 0; nt < 8; nt++) {
            const int vr = (nt * 16 + n16) * 64;
            short8 vf0 = *(const short8*)(Vs + vr + ((quad       ^ (n16 & 7)) * 8));
            short8 vf1 = *(const short8*)(Vs + vr + (((quad + 4) ^ (n16 & 7)) * 8));
            of[nt] = __builtin_amdgcn_mfma_f32_16x16x32_bf16(pf0, vf0, of[nt], 0, 0, 0);
            of[nt] = __builtin_amdgcn_mfma_f32_16x16x32_bf16(pf1, vf1, of[nt], 0, 0, 0);
        }
    }

    const int b = bh >> 4, h = bh & 15;
    #pragma unroll
    for (int r = 0; r < 4; r++) {
        const float inv = 1.f / lrow[r];
        const size_t orow = ((size_t)b * T_ + q0w + quad*4 + r) * H_ + h * HD_;
        #pragma unroll
        for (int nt = 0; nt < 8; nt++)
            o[orow + nt*16 + n16] = f2bf(of[nt][r] * inv);
    }
}

extern "C" void kernel_launch(void* const* d_in, const int* in_sizes, int n_in,
                              void* d_out, int out_size, void* d_ws, size_t ws_size,
                              hipStream_t stream)
{
    const float* x    = (const float*)d_in[0];
    const float* cosp = (const float*)d_in[1];
    const float* sinp = (const float*)d_in[2];
    const float* Wq   = (const float*)d_in[3];
    const float* Wk   = (const float*)d_in[4];
    const float* Wv   = (const float*)d_in[5];
    const float* Wo   = (const float*)d_in[6];

    const size_t NEL  = (size_t)B_ * T_ * H_;   // 8388608
    const int    XN   = (int)NEL;
    const int    WN   = H_ * H_;                // 4194304 per weight
    char* ws = (char*)d_ws;
    const size_t MB16 = 16777216;               // 16 MiB unit

    // overlay plan (total 7*MB16 = 117.4 MB):
    unsigned short* xh    = (unsigned short*)(ws);                // [0,1)   16.78MB
    unsigned short* Wqkvh = (unsigned short*)(ws + MB16);         // [1,2.5) 25.17MB
    unsigned short* Woh   = (unsigned short*)(ws + MB16*5/2);     // [2.5,3)  8.39MB
    unsigned short* qkvp  = (unsigned short*)(ws + 3*MB16);       // [3,6)   50.33MB
    unsigned short* kh    = (unsigned short*)(ws + 6*MB16);       // [6,7)   16.78MB
    unsigned short* qh    = (unsigned short*)(ws + MB16);         // overlays dead Wqkvh
    unsigned short* vh    = (unsigned short*)(ws);                // overlays dead xh
    unsigned short* abh   = (unsigned short*)(ws + 3*MB16);       // overlays dead qkvp

    f32_to_bf16<<<XN/1024, 256, 0, stream>>>(x,  xh,  XN);
    f32_to_bf16<<<WN/1024, 256, 0, stream>>>(Wq, Wqkvh,          WN);
    f32_to_bf16<<<WN/1024, 256, 0, stream>>>(Wk, Wqkvh +   WN,   WN);
    f32_to_bf16<<<WN/1024, 256, 0, stream>>>(Wv, Wqkvh + 2*WN,   WN);
    f32_to_bf16<<<WN/1024, 256, 0, stream>>>(Wo, Woh,            WN);

    const int M = B_ * T_;

    // fused QKV projection: [4096,2048] x [6144,2048]^T -> [4096,6144]
    // 128x256 tile -> 24x32 = 768 blocks = 3.0 exact rounds
    gemm_t<4, 4, true><<<dim3(QKVN/256, M/128), 512, 0, stream>>>(
        xh, Wqkvh, nullptr, qkvp, M, QKVN, H_);

    rope_convert_qk<<<(B_*T_*NH_*64)/256, 256, 0, stream>>>(qkvp, cosp, sinp, qh, kh);
    transpose_v<<<dim3(T_/64, HD_/64, B_*NH_), 256, 0, stream>>>(qkvp, vh);

    attn_mfma<<<dim3(T_/64, B_*NH_), 256, 0, stream>>>(qh, kh, vh, abh);

    // output projection: [4096,2048] x [2048,2048]^T -> [4096,2048] f32
    // 128x256 tile -> 8x32 = 256 blocks = 1.0 round
    gemm_t<4, 4, false><<<dim3(H_/256, M/128), 512, 0, stream>>>(
        abh, Woh, (float*)d_out, nullptr, M, H_, H_);
}